// Round 8
// baseline (166.033 us; speedup 1.0000x reference)
//
#include <hip/hip_runtime.h>
#include <hip/hip_bf16.h>
#include <math.h>

#define NB 32768
#define DD 128
#define HH 512
#define EE 16

typedef __attribute__((ext_vector_type(8))) short short8;
typedef __attribute__((ext_vector_type(4))) float f32x4;

__device__ __forceinline__ unsigned int pk_bf16(float a, float b) {
  float2 t; t.x = a; t.y = b;
  __hip_bfloat162 h = __float22bfloat162_rn(t);
  union { __hip_bfloat162 h; unsigned int u; } cv; cv.h = h;
  return cv.u;
}

// Abramowitz-Stegun 7.1.25 erf (3-term), |eps| <= 2.5e-5 (<< bf16 ulp of H)
__device__ __forceinline__ float gelu_f(float v) {
  float z = v * 0.70710678118654752f;
  float a = fabsf(z);
  float t = 1.0f / (1.0f + 0.47047f * a);
  float y = t * (0.3480242f + t * (-0.0958798f + t * 0.7478556f));
  float r = 1.0f - y * __expf(-a * a);
  r = z < 0.0f ? -r : r;
  return 0.5f * v * (1.0f + r);
}

// ---------------- fused prep: gate (bid<512) + weight transpose (512..1023) ----
// Gate: wg held in REGISTERS; rows looped 2-at-a-time (ILP in shuffle chains).
__global__ __launch_bounds__(256, 3) void prep_kernel(
    const float* __restrict__ x, const float* __restrict__ w1,
    const float* __restrict__ w2, const float* __restrict__ wg,
    const float* __restrict__ bg,
    unsigned short* __restrict__ w1T, unsigned short* __restrict__ w2T,
    int* __restrict__ counts, int* __restrict__ rows) {
  __shared__ __align__(16) char smem[34816];

  int tid = threadIdx.x;
  int bid = blockIdx.x;

  if (bid < 512) {
    float (*sx)[132] = (float(*)[132])smem;      // 64 rows x 128 (pad 132)
    int* lslot = (int*)(smem + 33792);
    int* lexp  = (int*)(smem + 34048);
    int* lcnt  = (int*)(smem + 34304);
    int* gbase = (int*)(smem + 34368);

    int base = bid * 64;
    if (tid < EE) lcnt[tid] = 0;
    {  // stage 64 x-rows coalesced: 4 threads/row, 32 cols each
      int r = tid >> 2, c0 = (tid & 3) * 32;
      const f32x4* src = (const f32x4*)(x + (size_t)(base + r) * DD + c0);
      #pragma unroll
      for (int i = 0; i < 8; ++i)
        *(f32x4*)&sx[r][c0 + i * 4] = src[i];
    }

    int wv = tid >> 6, l = tid & 63;
    int ep = l & 7;        // expert pair: experts {2ep, 2ep+1}
    int ds = l >> 3;       // d-slice: d in [ds*16, ds*16+16)

    // wg slice in registers: loaded ONCE (fp64 exact, validated R1-R7)
    double wr0[16], wr1[16];
    {
      const float* wp = wg + (ds * 16) * EE + 2 * ep;
      #pragma unroll
      for (int i = 0; i < 16; ++i) {
        float2 w2v = *(const float2*)(wp + i * EE);
        wr0[i] = (double)w2v.x; wr1[i] = (double)w2v.y;
      }
    }
    double bg0 = (double)bg[2 * ep], bg1 = (double)bg[2 * ep + 1];
    __syncthreads();

    // 2 rows per iteration: independent FMA + shuffle chains interleave
    for (int rr = 0; rr < 16; rr += 2) {
      int rowA = wv * 16 + rr, rowB = rowA + 1;
      double a0 = 0.0, a1 = 0.0, c0 = 0.0, c1 = 0.0;
      #pragma unroll
      for (int i = 0; i < 4; ++i) {
        f32x4 xa = *(const f32x4*)&sx[rowA][ds * 16 + i * 4];
        f32x4 xb = *(const f32x4*)&sx[rowB][ds * 16 + i * 4];
        #pragma unroll
        for (int c = 0; c < 4; ++c) {
          double xda = (double)xa[c], xdb = (double)xb[c];
          a0 += xda * wr0[i * 4 + c];
          a1 += xda * wr1[i * 4 + c];
          c0 += xdb * wr0[i * 4 + c];
          c1 += xdb * wr1[i * 4 + c];
        }
      }
      #pragma unroll
      for (int off = 8; off < 64; off <<= 1) {
        a0 += __shfl_xor(a0, off); a1 += __shfl_xor(a1, off);
        c0 += __shfl_xor(c0, off); c1 += __shfl_xor(c1, off);
      }
      a0 += bg0; a1 += bg1; c0 += bg0; c1 += bg1;
      double bvA = a0; int beA = 2 * ep;
      if (a1 > a0) { bvA = a1; beA = 2 * ep + 1; }
      double bvB = c0; int beB = 2 * ep;
      if (c1 > c0) { bvB = c1; beB = 2 * ep + 1; }
      #pragma unroll
      for (int off = 1; off < 8; off <<= 1) {
        double ovA = __shfl_xor(bvA, off); int oeA = __shfl_xor(beA, off);
        double ovB = __shfl_xor(bvB, off); int oeB = __shfl_xor(beB, off);
        if (ovA > bvA || (ovA == bvA && oeA < beA)) { bvA = ovA; beA = oeA; }
        if (ovB > bvB || (ovB == bvB && oeB < beB)) { bvB = ovB; beB = oeB; }
      }
      if (l == 0) {
        lslot[rowA] = atomicAdd(&lcnt[beA], 1); lexp[rowA] = beA;
        lslot[rowB] = atomicAdd(&lcnt[beB], 1); lexp[rowB] = beB;
      }
    }
    __syncthreads();
    if (tid < EE && lcnt[tid] > 0)
      gbase[tid] = atomicAdd(&counts[tid * 16], lcnt[tid]);
    __syncthreads();
    if (tid < 64) {
      int e2 = lexp[tid];
      rows[e2 * NB + gbase[e2] + lslot[tid]] = base + tid;
    }
  } else {
    // ---- transpose+cast: 64x64 fp32 tile -> bf16 transposed (verified R4-R7) ----
    float* sT = (float*)smem;   // [64][65]
    int tb = bid - 512;
    const float* src; unsigned short* dst; int sstride, dstride;
    if (tb < 256) {  // w1 (E,D,H) -> w1T (E,H,D)
      int e2 = tb >> 4, t = tb & 15;
      int d0 = (t >> 3) * 64, h0 = (t & 7) * 64;
      src = w1 + ((size_t)e2 * DD + d0) * HH + h0; sstride = HH;
      dst = w1T + (size_t)e2 * HH * DD + (size_t)h0 * DD + d0; dstride = DD;
    } else {         // w2 (E,H,D) -> w2T (E,D,H)
      int t2 = tb - 256;
      int e2 = t2 >> 4, t = t2 & 15;
      int h0 = (t >> 1) * 64, d0 = (t & 1) * 64;
      src = w2 + ((size_t)e2 * HH + h0) * DD + d0; sstride = DD;
      dst = w2T + (size_t)e2 * DD * HH + (size_t)d0 * HH + h0; dstride = HH;
    }
    int rr = tid >> 4, c4 = tid & 15;
    #pragma unroll
    for (int j = 0; j < 4; ++j) {
      int sr = rr + 16 * j;
      f32x4 v = *(const f32x4*)(src + (size_t)sr * sstride + c4 * 4);
      #pragma unroll
      for (int i = 0; i < 4; ++i) sT[sr * 65 + c4 * 4 + i] = v[i];
    }
    __syncthreads();
    #pragma unroll
    for (int j = 0; j < 4; ++j) {
      int R = rr + 16 * j;
      float f0 = sT[(4 * c4 + 0) * 65 + R];
      float f1 = sT[(4 * c4 + 1) * 65 + R];
      float f2 = sT[(4 * c4 + 2) * 65 + R];
      float f3 = sT[(4 * c4 + 3) * 65 + R];
      uint2 pkd; pkd.x = pk_bf16(f0, f1); pkd.y = pk_bf16(f2, f3);
      *(uint2*)(dst + (size_t)R * dstride + 4 * c4) = pkd;
    }
  }
}

// ---------------- grouped expert GEMM: TM=64 + register-prefetch pipeline -------
// Next chunk's global loads issue BEFORE compute; LDS write after post-compute
// barrier (vmcnt drain hidden behind MFMA/VALU).
__global__ __launch_bounds__(256, 3) void moe_gemm(
    const float* __restrict__ x, const unsigned short* __restrict__ w1T,
    const unsigned short* __restrict__ w2T, const int* __restrict__ counts,
    const int* __restrict__ rows, float* __restrict__ out) {
  int e = blockIdx.y;
  int cnt = counts[e * 16];
  int base = blockIdx.x * 64;
  if (base >= cnt) return;

  __shared__ unsigned short sW1[64][136];   // w1T chunk [h_local][d], pad 8
  __shared__ unsigned short sW2[DD][72];    // w2T chunk [d][h_local], pad 8
  __shared__ unsigned short sH[4][16][72];  // per-wave hidden [m][h_local]

  int tid = threadIdx.x;
  int wv = tid >> 6, l = tid & 63;
  int lm = l & 15, q = l >> 4;

  int i0 = base + wv * 16 + lm;
  int ci0 = i0 < cnt ? i0 : cnt - 1;
  int grow = rows[e * NB + ci0];

  const unsigned short* w1e = w1T + (size_t)e * HH * DD;
  const unsigned short* w2e = w2T + (size_t)e * DD * HH;

  // staging helpers (uniform index math, hoisted)
  int u2r = tid >> 3, u2c = tid & 7;  // for i=0 of w2; others add 32 rows
  uint4 p1[4], p2[4];
  auto load_chunk = [&](int hc) {
    int h0 = hc * 64;
    const uint4* s1 = (const uint4*)(w1e + (size_t)h0 * DD);
    #pragma unroll
    for (int i = 0; i < 4; ++i) p1[i] = s1[tid + i * 256];
    #pragma unroll
    for (int i = 0; i < 4; ++i)
      p2[i] = ((const uint4*)(w2e + (size_t)(u2r + i * 32) * HH + h0))[u2c];
  };
  auto write_chunk = [&]() {
    #pragma unroll
    for (int i = 0; i < 4; ++i) {
      int u = tid + i * 256;
      *(uint4*)&sW1[u >> 4][(u & 15) * 8] = p1[i];
    }
    #pragma unroll
    for (int i = 0; i < 4; ++i)
      *(uint4*)&sW2[u2r + i * 32][u2c * 8] = p2[i];
  };

  // X fragments in registers: xf[ks] = x[row][d = ks*32+q*8 .. +7] bf16
  short8 xf[4];
  {
    const float* xr = x + (size_t)grow * DD;
    #pragma unroll
    for (int ks = 0; ks < 4; ++ks) {
      const f32x4* p = (const f32x4*)(xr + ks * 32 + q * 8);
      f32x4 v0 = p[0], v1 = p[1];
      union { short8 s; unsigned int u[4]; } pk;
      pk.u[0] = pk_bf16(v0[0], v0[1]);
      pk.u[1] = pk_bf16(v0[2], v0[3]);
      pk.u[2] = pk_bf16(v1[0], v1[1]);
      pk.u[3] = pk_bf16(v1[2], v1[3]);
      xf[ks] = pk.s;
    }
  }

  f32x4 acc[8];  // lane holds out[m=lm][d = dt*16 + q*4 + r]
  #pragma unroll
  for (int dt = 0; dt < 8; ++dt) acc[dt] = (f32x4){0.f, 0.f, 0.f, 0.f};

  load_chunk(0);
  write_chunk();
  __syncthreads();

  for (int hc = 0; hc < 8; ++hc) {
    if (hc < 7) load_chunk(hc + 1);  // in flight during compute

    // GEMM1 (flipped): A = w1 frags from LDS, B = x register frags
    #pragma unroll
    for (int ht = 0; ht < 4; ++ht) {
      f32x4 ha = (f32x4){0.f, 0.f, 0.f, 0.f};
      #pragma unroll
      for (int ks = 0; ks < 4; ++ks) {
        short8 a = *(const short8*)&sW1[ht * 16 + lm][ks * 32 + q * 8];
        ha = __builtin_amdgcn_mfma_f32_16x16x32_bf16(a, xf[ks], ha, 0, 0, 0);
      }
      uint2 wa;
      wa.x = pk_bf16(gelu_f(ha[0]), gelu_f(ha[1]));
      wa.y = pk_bf16(gelu_f(ha[2]), gelu_f(ha[3]));
      *(uint2*)&sH[wv][lm][ht * 16 + q * 4] = wa;  // per-wave private
    }

    // GEMM2 (flipped): A = w2 frags from LDS, B = H frags from private LDS
    #pragma unroll
    for (int ks = 0; ks < 2; ++ks) {
      short8 b0 = *(const short8*)&sH[wv][lm][ks * 32 + q * 8];
      #pragma unroll
      for (int dt = 0; dt < 8; ++dt) {
        short8 a = *(const short8*)&sW2[dt * 16 + lm][ks * 32 + q * 8];
        acc[dt] = __builtin_amdgcn_mfma_f32_16x16x32_bf16(a, b0, acc[dt], 0, 0, 0);
      }
    }
    __syncthreads();              // all waves done reading chunk hc
    if (hc < 7) {
      write_chunk();              // vmcnt drain lands here, post-compute
      __syncthreads();
    }
  }

  // epilogue: float4 stores (top-1 softmax score == 1.0)
  if (i0 < cnt) {
    float* op = out + (size_t)grow * DD + q * 4;
    #pragma unroll
    for (int dt = 0; dt < 8; ++dt)
      *(f32x4*)(op + dt * 16) = acc[dt];
  }
}

extern "C" void kernel_launch(void* const* d_in, const int* in_sizes, int n_in,
                              void* d_out, int out_size, void* d_ws, size_t ws_size,
                              hipStream_t stream) {
  const float* x  = (const float*)d_in[0];
  const float* w1 = (const float*)d_in[1];
  const float* w2 = (const float*)d_in[2];
  const float* wg = (const float*)d_in[3];
  const float* bg = (const float*)d_in[4];
  float* out = (float*)d_out;

  // ws: [0,1024) counts padded 64B/expert | [1024,+2MB) rows | w1T 2MB | w2T 2MB
  int* counts = (int*)d_ws;               // counts[e] at int index e*16
  int* rows   = (int*)((char*)d_ws + 1024);
  unsigned short* w1T = (unsigned short*)((char*)d_ws + 1024 + (size_t)EE * NB * 4);
  unsigned short* w2T = w1T + (size_t)EE * HH * DD;

  hipMemsetAsync(d_ws, 0, 1024, stream);
  hipLaunchKernelGGL(prep_kernel, dim3(1024), dim3(256), 0, stream,
                     x, w1, w2, wg, bg, w1T, w2T, counts, rows);
  hipLaunchKernelGGL(moe_gemm, dim3(NB / 64, EE), dim3(256), 0, stream,
                     x, w1T, w2T, counts, rows, out);
}